// Round 1
// baseline (258.919 us; speedup 1.0000x reference)
//
#include <hip/hip_runtime.h>

#define IN_DIM 8192
#define OUT_DIM 8192
#define NROWS 4096

// GATE_COEF[16][4] from the reference.
__device__ __constant__ float GATE_COEF[16][4] = {
    {0.f, 0.f, 0.f, 0.f}, {0.f, 0.f, 0.f, 1.f}, {0.f, 1.f, 0.f, -1.f}, {0.f, 1.f, 0.f, 0.f},
    {0.f, 0.f, 1.f, -1.f}, {0.f, 0.f, 1.f, 0.f}, {0.f, 1.f, 1.f, -2.f}, {0.f, 1.f, 1.f, -1.f},
    {1.f, -1.f, -1.f, 1.f}, {1.f, -1.f, -1.f, 2.f}, {1.f, 0.f, -1.f, 0.f}, {1.f, 0.f, -1.f, 1.f},
    {1.f, -1.f, 0.f, 0.f}, {1.f, -1.f, 0.f, 1.f}, {1.f, 0.f, 0.f, -1.f}, {1.f, 0.f, 0.f, 0.f}};

// Kernel A: c[j] = softmax(weights[j,:]) @ GATE_COEF  -> float4 per j
__global__ __launch_bounds__(256) void compute_c_kernel(const float* __restrict__ w,
                                                        float4* __restrict__ c) {
    int j = blockIdx.x * blockDim.x + threadIdx.x;
    if (j >= OUT_DIM) return;
    const float4* wv = (const float4*)(w + (size_t)j * 16);
    float4 w0 = wv[0], w1 = wv[1], w2 = wv[2], w3 = wv[3];
    float wa[16] = {w0.x, w0.y, w0.z, w0.w, w1.x, w1.y, w1.z, w1.w,
                    w2.x, w2.y, w2.z, w2.w, w3.x, w3.y, w3.z, w3.w};
    float m = wa[0];
#pragma unroll
    for (int k = 1; k < 16; ++k) m = fmaxf(m, wa[k]);
    float p[16];
    float s = 0.f;
#pragma unroll
    for (int k = 0; k < 16; ++k) {
        p[k] = __expf(wa[k] - m);
        s += p[k];
    }
    float inv = 1.f / s;
    float c0 = 0.f, c1 = 0.f, c2 = 0.f, c3 = 0.f;
#pragma unroll
    for (int k = 0; k < 16; ++k) {
        c0 = fmaf(p[k], GATE_COEF[k][0], c0);
        c1 = fmaf(p[k], GATE_COEF[k][1], c1);
        c2 = fmaf(p[k], GATE_COEF[k][2], c2);
        c3 = fmaf(p[k], GATE_COEF[k][3], c3);
    }
    c[j] = make_float4(c0 * inv, c1 * inv, c2 * inv, c3 * inv);
}

// Kernel B: one block per row i. Stage x[i,:] (32 KB) in LDS, gather, fused gate eval.
__global__ __launch_bounds__(256) void gate_kernel(const float* __restrict__ x,
                                                   const float4* __restrict__ c,
                                                   const int* __restrict__ idx0,
                                                   const int* __restrict__ idx1,
                                                   float* __restrict__ out) {
    __shared__ float row[IN_DIM];
    const int i = blockIdx.x;
    const float4* xr = (const float4*)(x + (size_t)i * IN_DIM);
    float4* rowv = (float4*)row;
#pragma unroll
    for (int t = 0; t < IN_DIM / 4 / 256; ++t) {
        rowv[threadIdx.x + t * 256] = xr[threadIdx.x + t * 256];
    }
    __syncthreads();

    float* orow = out + (size_t)i * OUT_DIM;
#pragma unroll
    for (int k = 0; k < OUT_DIM / 1024; ++k) {
        const int j = k * 1024 + threadIdx.x * 4;
        const int4 i0 = *(const int4*)(idx0 + j);
        const int4 i1 = *(const int4*)(idx1 + j);
        const float4 ca = c[j + 0];
        const float4 cb = c[j + 1];
        const float4 cc = c[j + 2];
        const float4 cd = c[j + 3];
        float a, b;
        float4 o;
        a = row[i0.x]; b = row[i1.x];
        o.x = fmaf(a * b, ca.w, fmaf(b, ca.z, fmaf(a, ca.y, ca.x)));
        a = row[i0.y]; b = row[i1.y];
        o.y = fmaf(a * b, cb.w, fmaf(b, cb.z, fmaf(a, cb.y, cb.x)));
        a = row[i0.z]; b = row[i1.z];
        o.z = fmaf(a * b, cc.w, fmaf(b, cc.z, fmaf(a, cc.y, cc.x)));
        a = row[i0.w]; b = row[i1.w];
        o.w = fmaf(a * b, cd.w, fmaf(b, cd.z, fmaf(a, cd.y, cd.x)));
        *(float4*)(orow + j) = o;
    }
}

extern "C" void kernel_launch(void* const* d_in, const int* in_sizes, int n_in,
                              void* d_out, int out_size, void* d_ws, size_t ws_size,
                              hipStream_t stream) {
    const float* x = (const float*)d_in[0];
    const float* weights = (const float*)d_in[1];
    const int* idx0 = (const int*)d_in[2];
    const int* idx1 = (const int*)d_in[3];
    float* out = (float*)d_out;
    float4* c = (float4*)d_ws;  // OUT_DIM float4s = 128 KB scratch

    compute_c_kernel<<<OUT_DIM / 256, 256, 0, stream>>>(weights, c);
    gate_kernel<<<NROWS, 256, 0, stream>>>(x, c, idx0, idx1, out);
}